// Round 2
// baseline (16095.174 us; speedup 1.0000x reference)
//
#include <hip/hip_runtime.h>
#include <cstdint>
#include <cstddef>

#define B_ 128
#define S_ 1024
#define I_ 128
#define H_ 256
#define G4 1024  // 4*H
#define OFF_SLOPE 0.001f

// ---------------------------------------------------------------------------
// Kernel A: Gx[b,t,:] = x[b,t,:] @ W + bias   (M = B*S = 131072, K = 128, N = 1024)
// One block = 16 rows of X, 256 threads, each thread owns 4 consecutive cols.
// W streamed from L2 (512 KB, resident), X rows staged in LDS.
// ---------------------------------------------------------------------------
__global__ __launch_bounds__(256) void gemm_xw(const float* __restrict__ X,
                                               const float* __restrict__ W,
                                               const float* __restrict__ bias,
                                               float* __restrict__ Gx) {
    __shared__ float A_s[16 * 128];
    const int tid = threadIdx.x;
    const size_t row0 = (size_t)blockIdx.x * 16;

    for (int i = tid; i < 16 * 128; i += 256)
        A_s[i] = X[row0 * I_ + i];
    __syncthreads();

    const float4 bias4 = ((const float4*)bias)[tid];
    float4 acc[16];
#pragma unroll
    for (int r = 0; r < 16; ++r) acc[r] = bias4;

    const float4* W4 = (const float4*)W;
    for (int k = 0; k < I_; ++k) {
        float4 w = W4[k * 256 + tid];
#pragma unroll
        for (int r = 0; r < 16; ++r) {
            float a = A_s[r * 128 + k];
            acc[r].x = fmaf(a, w.x, acc[r].x);
            acc[r].y = fmaf(a, w.y, acc[r].y);
            acc[r].z = fmaf(a, w.z, acc[r].z);
            acc[r].w = fmaf(a, w.w, acc[r].w);
        }
    }
    float4* O4 = (float4*)Gx;
#pragma unroll
    for (int r = 0; r < 16; ++r)
        O4[(row0 + r) * 256 + tid] = acc[r];
}

// ---------------------------------------------------------------------------
// Kernel B: sequential phased-LSTM scan, NB=2 batches per block.
// 64 blocks (one per batch pair), 512 threads.
//   - gate phase: thread owns gate columns {2*tid, 2*tid+1} for BOTH batches;
//     each 8B U load feeds 4 FMAs (2 cols x 2 batches) -> halves L2 U traffic
//     vs one-batch-per-block.
//   - elementwise phase: thread handles (batch = tid>>8, unit = tid&255).
// PRE=true : x@W+bias preactivations read from Gx (workspace).
// PRE=false: computed on the fly (no workspace needed).
// ---------------------------------------------------------------------------
template <bool PRE>
__global__ __launch_bounds__(512) void plstm_scan2(
    const float* __restrict__ x, const float* __restrict__ ts,
    const float* __restrict__ W, const float* __restrict__ U,
    const float* __restrict__ bias, const float* __restrict__ Periods,
    const float* __restrict__ Shifts, const float* __restrict__ OnEnd,
    const float* __restrict__ Gx, float* __restrict__ out) {
    const int g = blockIdx.x;       // batch pair index
    const int tid = threadIdx.x;
    const int lane = tid & 255;     // hidden unit owned in elementwise phase
    const int bb = tid >> 8;        // which batch of the pair in elementwise
    const int b0 = 2 * g, b1 = 2 * g + 1;
    const int bcur = b0 + bb;

    __shared__ float h_s[2][H_];
    __shared__ float gate_s[2][G4];
    __shared__ float x_s[2][I_];

    // phase-gate params for `lane` (same in both halves of the block)
    const float period = fabsf(Periods[lane]);
    const float shift = Shifts[lane];
    const float oe = fabsf(OnEnd[lane]);
    const float on_mid = oe * 0.5f * period;
    const float on_end = oe * period;
    const float inv_on_mid = 1.0f / on_mid;
    const float inv_period = 1.0f / period;

    ((float*)h_s)[tid] = 0.f;   // zero both batches' h

    float c = 0.f, last_h = 0.f;
    float2 bias2 = make_float2(0.f, 0.f);
    if (!PRE) bias2 = ((const float2*)bias)[tid];

    const float2* W2 = (const float2*)W;
    const float2* U2 = (const float2*)U;
    const float2* Gx2 = (const float2*)Gx;
    const float* tsb = ts + (size_t)bcur * S_;
    const size_t obase = (size_t)bcur * S_ * H_;

    for (int t = 0; t < S_; ++t) {
        if (!PRE) {
            if (tid < 2 * I_)
                x_s[tid >> 7][tid & 127] =
                    x[((size_t)(b0 + (tid >> 7)) * S_ + t) * I_ + (tid & 127)];
        }
        __syncthreads();  // B1: h_s(t-1)/x_s ready; prev-step gate_s reads done

        float2 a0, a1;
        if (PRE) {
            a0 = Gx2[((size_t)b0 * S_ + t) * (G4 / 2) + tid];
            a1 = Gx2[((size_t)b1 * S_ + t) * (G4 / 2) + tid];
        } else {
            a0 = bias2;
            a1 = bias2;
#pragma unroll 8
            for (int k = 0; k < I_; ++k) {
                float2 w = W2[k * (G4 / 2) + tid];
                float x0 = x_s[0][k], x1 = x_s[1][k];
                a0.x = fmaf(x0, w.x, a0.x);
                a0.y = fmaf(x0, w.y, a0.y);
                a1.x = fmaf(x1, w.x, a1.x);
                a1.y = fmaf(x1, w.y, a1.y);
            }
        }
#pragma unroll 8
        for (int k = 0; k < H_; ++k) {
            float2 u = U2[k * (G4 / 2) + tid];
            float h0 = h_s[0][k], h1 = h_s[1][k];
            a0.x = fmaf(h0, u.x, a0.x);
            a0.y = fmaf(h0, u.y, a0.y);
            a1.x = fmaf(h1, u.x, a1.x);
            a1.y = fmaf(h1, u.y, a1.y);
        }
        ((float2*)gate_s[0])[tid] = a0;
        ((float2*)gate_s[1])[tid] = a1;
        __syncthreads();  // B2: gates ready; all h_s reads of this step done

        {
            float ig = gate_s[bb][lane];
            float fg = gate_s[bb][H_ + lane];
            float gg = gate_s[bb][2 * H_ + lane];
            float og = gate_s[bb][3 * H_ + lane];
            float i_t = 1.f / (1.f + expf(-ig));
            float f_t = 1.f / (1.f + expf(-fg));
            float g_t = tanhf(gg);
            float o_t = 1.f / (1.f + expf(-og));
            float hp = h_s[bb][lane];
            float c_new = fmaf(f_t, c, i_t * g_t);
            float h_new = o_t * tanhf(c_new);

            float tv = tsb[t];
            float in_c = fmodf(tv + shift, period);
            float mask;
            if (in_c <= on_mid)
                mask = in_c * inv_on_mid;
            else if (in_c <= on_end)
                mask = (on_end - in_c) * inv_on_mid;
            else
                mask = OFF_SLOPE * (in_c * inv_period);

            c = mask * c_new + (1.f - mask) * c;
            float h2 = mask * h_new + (1.f - mask) * hp;
            h_s[bb][lane] = h2;  // sole reader/writer of this slot until B1
            out[obase + (size_t)t * H_ + lane] = h2;
            last_h = h2;
        }
    }

    // h_T then c_T, concatenated after hidden_seq
    out[(size_t)B_ * S_ * H_ + (size_t)bcur * H_ + lane] = last_h;
    out[(size_t)B_ * S_ * H_ + (size_t)B_ * H_ + (size_t)bcur * H_ + lane] = c;
}

// ---------------------------------------------------------------------------
extern "C" void kernel_launch(void* const* d_in, const int* in_sizes, int n_in,
                              void* d_out, int out_size, void* d_ws, size_t ws_size,
                              hipStream_t stream) {
    (void)in_sizes; (void)n_in; (void)out_size;
    const float* x = (const float*)d_in[0];
    const float* ts = (const float*)d_in[1];
    const float* W = (const float*)d_in[2];
    const float* U = (const float*)d_in[3];
    const float* bias = (const float*)d_in[4];
    const float* Periods = (const float*)d_in[5];
    const float* Shifts = (const float*)d_in[6];
    const float* OnEnd = (const float*)d_in[7];
    float* out = (float*)d_out;

    const size_t gx_bytes = (size_t)B_ * S_ * G4 * sizeof(float);
    if (ws_size >= gx_bytes) {
        float* Gx = (float*)d_ws;
        gemm_xw<<<(B_ * S_) / 16, 256, 0, stream>>>(x, W, bias, Gx);
        plstm_scan2<true><<<B_ / 2, 512, 0, stream>>>(x, ts, W, U, bias, Periods,
                                                      Shifts, OnEnd, Gx, out);
    } else {
        plstm_scan2<false><<<B_ / 2, 512, 0, stream>>>(x, ts, W, U, bias, Periods,
                                                       Shifts, OnEnd, nullptr, out);
    }
}

// Round 3
// 9941.635 us; speedup vs baseline: 1.6190x; 1.6190x over previous
//
#include <hip/hip_runtime.h>
#include <cstdint>
#include <cstddef>

#define B_ 128
#define S_ 1024
#define I_ 128
#define H_ 256
#define G4 1024  // 4*H
#define OFF_SLOPE 0.001f

typedef float f32x4 __attribute__((ext_vector_type(4)));
typedef short s16x8 __attribute__((ext_vector_type(8)));

__device__ __forceinline__ unsigned short f2bf_rne(float f) {
    unsigned int u = __builtin_bit_cast(unsigned int, f);
    u += 0x7FFFu + ((u >> 16) & 1u);
    return (unsigned short)(u >> 16);
}
__device__ __forceinline__ float bf2f(unsigned short h) {
    unsigned int u = ((unsigned int)h) << 16;
    return __builtin_bit_cast(float, u);
}

// ---------------------------------------------------------------------------
// Kernel A: Gx = x @ W + bias.  SCANLAYOUT=true writes the MFMA-scan-friendly
// order [group][colblock][t][16 b][128 lc]; false writes plain [b,t,1024].
// ---------------------------------------------------------------------------
template <bool SCANLAYOUT>
__global__ __launch_bounds__(256) void gemm_xw(const float* __restrict__ X,
                                               const float* __restrict__ W,
                                               const float* __restrict__ bias,
                                               float* __restrict__ Gx) {
    __shared__ float A_s[16 * 128];
    const int tid = threadIdx.x;
    const size_t row0 = (size_t)blockIdx.x * 16;

    for (int i = tid; i < 16 * 128; i += 256)
        A_s[i] = X[row0 * I_ + i];
    __syncthreads();

    const float4 bias4 = ((const float4*)bias)[tid];
    float4 acc[16];
#pragma unroll
    for (int r = 0; r < 16; ++r) acc[r] = bias4;

    const float4* W4 = (const float4*)W;
    for (int k = 0; k < I_; ++k) {
        float4 w = W4[k * 256 + tid];
#pragma unroll
        for (int r = 0; r < 16; ++r) {
            float a = A_s[r * 128 + k];
            acc[r].x = fmaf(a, w.x, acc[r].x);
            acc[r].y = fmaf(a, w.y, acc[r].y);
            acc[r].z = fmaf(a, w.z, acc[r].z);
            acc[r].w = fmaf(a, w.w, acc[r].w);
        }
    }
    if (SCANLAYOUT) {
        const int b = (int)(row0 >> 10);       // S_=1024
        const int t0 = (int)(row0 & 1023);
        const int g = b >> 4, bb = b & 15;
        const int n0 = 4 * tid;
        const int q = n0 >> 8, u = n0 & 255, cb = u >> 5, j = u & 31;
        const int lc = q * 32 + j;
#pragma unroll
        for (int r = 0; r < 16; ++r) {
            size_t idx = ((((size_t)(g * 8 + cb) * 1024 + (t0 + r)) * 16 + bb) * 128 + lc);
            *(float4*)&Gx[idx] = acc[r];
        }
    } else {
        float4* O4 = (float4*)Gx;
#pragma unroll
        for (int r = 0; r < 16; ++r)
            O4[(row0 + r) * 256 + tid] = acc[r];
    }
}

// ---------------------------------------------------------------------------
// Kernel B (new): MFMA phased-LSTM scan.
// Grid = 64 blocks x 256 threads. Block (g, cb): g = batch group of 16,
// cb = column-block owning hidden units [32*cb, 32*cb+32).
// U slice (256 x 128 cols) lives in REGISTERS as split-bf16 (hi+lo) MFMA
// B-fragments. h exchanged between the 8 sibling blocks per step through a
// global double buffer + device-scope flags (all 64 blocks co-resident:
// 64 <= 256 CUs). Per-thread c/h state stays fp32 in registers.
// ---------------------------------------------------------------------------
__global__ __launch_bounds__(256, 1) void plstm_mfma(
    const float* __restrict__ ts, const float* __restrict__ U,
    const float* __restrict__ Periods, const float* __restrict__ Shifts,
    const float* __restrict__ OnEnd, const float* __restrict__ Gx,
    float* __restrict__ out, unsigned short* __restrict__ hbuf,
    int* __restrict__ flags) {
    const int blk = blockIdx.x;
    const int g = blk >> 3;
    const int cb = blk & 7;
    const int tid = threadIdx.x;
    const int w = tid >> 6;   // wave = gate index q
    const int l = tid & 63;
    const int lr = l & 15;    // tile row/col lane
    const int lg = l >> 4;    // k-group

    __shared__ unsigned short h_hi[16 * 264];
    __shared__ unsigned short h_lo[16 * 264];
    __shared__ float gates[4 * 16 * 33];

    // ---- stage U slice into registers as split-bf16 B-fragments ----
    // B-frag (16x16x32): lane l holds B[k=(l>>4)*8+i][col=l&15], i=0..7
    s16x8 Uhi[2][8], Ulo[2][8];
#pragma unroll
    for (int tt = 0; tt < 2; ++tt) {
        const int n = w * 256 + cb * 32 + tt * 16 + lr;  // global gate col
#pragma unroll
        for (int kk = 0; kk < 8; ++kk) {
            s16x8 hi8, lo8;
#pragma unroll
            for (int i = 0; i < 8; ++i) {
                int k = kk * 32 + lg * 8 + i;
                float uv = U[(size_t)k * G4 + n];
                unsigned short h = f2bf_rne(uv);
                float r = uv - bf2f(h);
                hi8[i] = (short)h;
                lo8[i] = (short)f2bf_rne(r);
            }
            Uhi[tt][kk] = hi8;
            Ulo[tt][kk] = lo8;
        }
    }

    // ---- elementwise identity: thread owns (batch eb, units u0, u0+1) ----
    const int eb = tid >> 4;
    const int ej = 2 * (tid & 15);
    const int u0 = cb * 32 + ej;  // global hidden unit
    const float per0 = fabsf(Periods[u0]), per1 = fabsf(Periods[u0 + 1]);
    const float sh0 = Shifts[u0], sh1 = Shifts[u0 + 1];
    const float oe0 = fabsf(OnEnd[u0]) * per0, oe1 = fabsf(OnEnd[u0 + 1]) * per1;
    const float om0 = 0.5f * oe0, om1 = 0.5f * oe1;
    const float iom0 = 1.0f / om0, iom1 = 1.0f / om1;
    const float ip0 = 1.0f / per0, ip1 = 1.0f / per1;

    float c0 = 0.f, c1 = 0.f, h0 = 0.f, h1 = 0.f;
    const float* tsrow = ts + (size_t)(g * 16 + eb) * S_;
    const float* gxbase = Gx + (size_t)(g * 8 + cb) * 1024 * 2048;
    float* outrow = out + (size_t)(g * 16 + eb) * S_ * H_ + u0;

    unsigned short* hbp[2][2];
#pragma unroll
    for (int p = 0; p < 2; ++p)
#pragma unroll
        for (int s = 0; s < 2; ++s)
            hbp[p][s] = hbuf + (((size_t)p * 8 + g) * 2 + s) * 4096;

    for (int i = tid; i < 16 * 264; i += 256) { h_hi[i] = 0; h_lo[i] = 0; }
    __syncthreads();

    const int abase = lr * 264 + lg * 8;

    for (int t = 0; t < S_; ++t) {
        // prefetch Gx + ts for the elementwise phase (consumed after barrier)
        const float* gxt = gxbase + (size_t)t * 2048 + eb * 128;
        float2 gq0 = *(const float2*)&gxt[0 * 32 + ej];
        float2 gq1 = *(const float2*)&gxt[1 * 32 + ej];
        float2 gq2 = *(const float2*)&gxt[2 * 32 + ej];
        float2 gq3 = *(const float2*)&gxt[3 * 32 + ej];
        float tsv = tsrow[t];

        // ---- MFMA: gates_partial = h @ Uslice (split-bf16, 3 products) ----
        f32x4 a0 = {0.f, 0.f, 0.f, 0.f}, a1 = {0.f, 0.f, 0.f, 0.f};
#pragma unroll
        for (int kk = 0; kk < 8; ++kk) {
            s16x8 ah = *(const s16x8*)&h_hi[abase + kk * 32];
            s16x8 al = *(const s16x8*)&h_lo[abase + kk * 32];
            a0 = __builtin_amdgcn_mfma_f32_16x16x32_bf16(ah, Uhi[0][kk], a0, 0, 0, 0);
            a0 = __builtin_amdgcn_mfma_f32_16x16x32_bf16(ah, Ulo[0][kk], a0, 0, 0, 0);
            a0 = __builtin_amdgcn_mfma_f32_16x16x32_bf16(al, Uhi[0][kk], a0, 0, 0, 0);
            a1 = __builtin_amdgcn_mfma_f32_16x16x32_bf16(ah, Uhi[1][kk], a1, 0, 0, 0);
            a1 = __builtin_amdgcn_mfma_f32_16x16x32_bf16(ah, Ulo[1][kk], a1, 0, 0, 0);
            a1 = __builtin_amdgcn_mfma_f32_16x16x32_bf16(al, Uhi[1][kk], a1, 0, 0, 0);
        }
        // C frag: row(batch) = lg*4+r, col = lr  -> gates[q][batch][jlocal]
#pragma unroll
        for (int r = 0; r < 4; ++r) {
            gates[(w * 16 + lg * 4 + r) * 33 + lr] = a0[r];
            gates[(w * 16 + lg * 4 + r) * 33 + 16 + lr] = a1[r];
        }
        __syncthreads();

        // ---- elementwise phased-LSTM update (2 units per thread) ----
        float i0 = gates[(0 * 16 + eb) * 33 + ej] + gq0.x;
        float f0 = gates[(1 * 16 + eb) * 33 + ej] + gq1.x;
        float g0 = gates[(2 * 16 + eb) * 33 + ej] + gq2.x;
        float o0 = gates[(3 * 16 + eb) * 33 + ej] + gq3.x;
        float i1 = gates[(0 * 16 + eb) * 33 + ej + 1] + gq0.y;
        float f1 = gates[(1 * 16 + eb) * 33 + ej + 1] + gq1.y;
        float g1 = gates[(2 * 16 + eb) * 33 + ej + 1] + gq2.y;
        float o1 = gates[(3 * 16 + eb) * 33 + ej + 1] + gq3.y;

        float it0 = 1.f / (1.f + expf(-i0)), ft0 = 1.f / (1.f + expf(-f0));
        float gt0 = tanhf(g0), ot0 = 1.f / (1.f + expf(-o0));
        float it1 = 1.f / (1.f + expf(-i1)), ft1 = 1.f / (1.f + expf(-f1));
        float gt1 = tanhf(g1), ot1 = 1.f / (1.f + expf(-o1));

        float cn0 = fmaf(ft0, c0, it0 * gt0);
        float hn0 = ot0 * tanhf(cn0);
        float cn1 = fmaf(ft1, c1, it1 * gt1);
        float hn1 = ot1 * tanhf(cn1);

        float ic0 = fmodf(tsv + sh0, per0);
        float m0 = (ic0 <= om0) ? ic0 * iom0
                 : (ic0 <= oe0) ? (oe0 - ic0) * iom0
                                : OFF_SLOPE * (ic0 * ip0);
        float ic1 = fmodf(tsv + sh1, per1);
        float m1 = (ic1 <= om1) ? ic1 * iom1
                 : (ic1 <= oe1) ? (oe1 - ic1) * iom1
                                : OFF_SLOPE * (ic1 * ip1);

        c0 = m0 * cn0 + (1.f - m0) * c0;
        c1 = m1 * cn1 + (1.f - m1) * c1;
        h0 = m0 * hn0 + (1.f - m0) * h0;
        h1 = m1 * hn1 + (1.f - m1) * h1;

        *(float2*)&outrow[(size_t)t * H_] = make_float2(h0, h1);

        // publish split-bf16 h to the group buffer (device-scope visible)
        unsigned int hiw = (unsigned int)f2bf_rne(h0) | ((unsigned int)f2bf_rne(h1) << 16);
        float r0 = h0 - bf2f(f2bf_rne(h0));
        float r1 = h1 - bf2f(f2bf_rne(h1));
        unsigned int low = (unsigned int)f2bf_rne(r0) | ((unsigned int)f2bf_rne(r1) << 16);
        const int hidx = (eb * 256 + u0) >> 1;
        __hip_atomic_store((unsigned int*)hbp[t & 1][0] + hidx, hiw,
                           __ATOMIC_RELAXED, __HIP_MEMORY_SCOPE_AGENT);
        __hip_atomic_store((unsigned int*)hbp[t & 1][1] + hidx, low,
                           __ATOMIC_RELAXED, __HIP_MEMORY_SCOPE_AGENT);
        __threadfence();
        __syncthreads();
        if (tid == 0)
            __hip_atomic_store(&flags[blk], t + 1, __ATOMIC_RELEASE,
                               __HIP_MEMORY_SCOPE_AGENT);
        if (tid < 8) {
            int guard = 0;
            while (__hip_atomic_load(&flags[g * 8 + tid], __ATOMIC_ACQUIRE,
                                     __HIP_MEMORY_SCOPE_AGENT) < t + 1) {
                if (++guard > (1 << 14)) break;  // bounded: never hang
            }
        }
        __syncthreads();

        // ---- refill h LDS (full 16x256, both halves) from group buffer ----
        {
            const unsigned short* src = (tid < 128) ? hbp[t & 1][0] : hbp[t & 1][1];
            unsigned short* dst = (tid < 128) ? h_hi : h_lo;
            const int tt2 = tid & 127;
            const int b2 = tt2 >> 3, seg = tt2 & 7;
            const uint4* s4 = (const uint4*)&src[b2 * 256 + seg * 32];
            uint4 v0 = s4[0], v1 = s4[1], v2 = s4[2], v3 = s4[3];
            uint4* d4 = (uint4*)&dst[b2 * 264 + seg * 32];
            d4[0] = v0; d4[1] = v1; d4[2] = v2; d4[3] = v3;
        }
        __syncthreads();
    }

    const size_t fin = (size_t)B_ * S_ * H_;
    *(float2*)&out[fin + (size_t)(g * 16 + eb) * H_ + u0] = make_float2(h0, h1);
    *(float2*)&out[fin + (size_t)B_ * H_ + (size_t)(g * 16 + eb) * H_ + u0] =
        make_float2(c0, c1);
}

// ---------------------------------------------------------------------------
// Fallback (round-2 verified): VALU scan, NB=2 batches/block.
// ---------------------------------------------------------------------------
template <bool PRE>
__global__ __launch_bounds__(512) void plstm_scan2(
    const float* __restrict__ x, const float* __restrict__ ts,
    const float* __restrict__ W, const float* __restrict__ U,
    const float* __restrict__ bias, const float* __restrict__ Periods,
    const float* __restrict__ Shifts, const float* __restrict__ OnEnd,
    const float* __restrict__ Gx, float* __restrict__ out) {
    const int g = blockIdx.x;
    const int tid = threadIdx.x;
    const int lane = tid & 255;
    const int bb = tid >> 8;
    const int b0 = 2 * g, b1 = 2 * g + 1;
    const int bcur = b0 + bb;

    __shared__ float h_s[2][H_];
    __shared__ float gate_s[2][G4];
    __shared__ float x_s[2][I_];

    const float period = fabsf(Periods[lane]);
    const float shift = Shifts[lane];
    const float oe = fabsf(OnEnd[lane]);
    const float on_mid = oe * 0.5f * period;
    const float on_end = oe * period;
    const float inv_on_mid = 1.0f / on_mid;
    const float inv_period = 1.0f / period;

    ((float*)h_s)[tid] = 0.f;

    float c = 0.f, last_h = 0.f;
    float2 bias2 = make_float2(0.f, 0.f);
    if (!PRE) bias2 = ((const float2*)bias)[tid];

    const float2* W2 = (const float2*)W;
    const float2* U2 = (const float2*)U;
    const float2* Gx2 = (const float2*)Gx;
    const float* tsb = ts + (size_t)bcur * S_;
    const size_t obase = (size_t)bcur * S_ * H_;

    for (int t = 0; t < S_; ++t) {
        if (!PRE) {
            if (tid < 2 * I_)
                x_s[tid >> 7][tid & 127] =
                    x[((size_t)(b0 + (tid >> 7)) * S_ + t) * I_ + (tid & 127)];
        }
        __syncthreads();

        float2 a0, a1;
        if (PRE) {
            a0 = Gx2[((size_t)b0 * S_ + t) * (G4 / 2) + tid];
            a1 = Gx2[((size_t)b1 * S_ + t) * (G4 / 2) + tid];
        } else {
            a0 = bias2; a1 = bias2;
#pragma unroll 8
            for (int k = 0; k < I_; ++k) {
                float2 w = W2[k * (G4 / 2) + tid];
                float x0 = x_s[0][k], x1 = x_s[1][k];
                a0.x = fmaf(x0, w.x, a0.x);
                a0.y = fmaf(x0, w.y, a0.y);
                a1.x = fmaf(x1, w.x, a1.x);
                a1.y = fmaf(x1, w.y, a1.y);
            }
        }
#pragma unroll 8
        for (int k = 0; k < H_; ++k) {
            float2 u = U2[k * (G4 / 2) + tid];
            float hv0 = h_s[0][k], hv1 = h_s[1][k];
            a0.x = fmaf(hv0, u.x, a0.x);
            a0.y = fmaf(hv0, u.y, a0.y);
            a1.x = fmaf(hv1, u.x, a1.x);
            a1.y = fmaf(hv1, u.y, a1.y);
        }
        ((float2*)gate_s[0])[tid] = a0;
        ((float2*)gate_s[1])[tid] = a1;
        __syncthreads();

        {
            float ig = gate_s[bb][lane];
            float fg = gate_s[bb][H_ + lane];
            float gg = gate_s[bb][2 * H_ + lane];
            float og = gate_s[bb][3 * H_ + lane];
            float i_t = 1.f / (1.f + expf(-ig));
            float f_t = 1.f / (1.f + expf(-fg));
            float g_t = tanhf(gg);
            float o_t = 1.f / (1.f + expf(-og));
            float hp = h_s[bb][lane];
            float c_new = fmaf(f_t, c, i_t * g_t);
            float h_new = o_t * tanhf(c_new);

            float tv = tsb[t];
            float in_c = fmodf(tv + shift, period);
            float mask;
            if (in_c <= on_mid) mask = in_c * inv_on_mid;
            else if (in_c <= on_end) mask = (on_end - in_c) * inv_on_mid;
            else mask = OFF_SLOPE * (in_c * inv_period);

            c = mask * c_new + (1.f - mask) * c;
            float h2 = mask * h_new + (1.f - mask) * hp;
            h_s[bb][lane] = h2;
            out[obase + (size_t)t * H_ + lane] = h2;
            last_h = h2;
        }
    }

    out[(size_t)B_ * S_ * H_ + (size_t)bcur * H_ + lane] = last_h;
    out[(size_t)B_ * S_ * H_ + (size_t)B_ * H_ + (size_t)bcur * H_ + lane] = c;
}

// ---------------------------------------------------------------------------
extern "C" void kernel_launch(void* const* d_in, const int* in_sizes, int n_in,
                              void* d_out, int out_size, void* d_ws, size_t ws_size,
                              hipStream_t stream) {
    (void)in_sizes; (void)n_in; (void)out_size;
    const float* x = (const float*)d_in[0];
    const float* ts = (const float*)d_in[1];
    const float* W = (const float*)d_in[2];
    const float* U = (const float*)d_in[3];
    const float* bias = (const float*)d_in[4];
    const float* Periods = (const float*)d_in[5];
    const float* Shifts = (const float*)d_in[6];
    const float* OnEnd = (const float*)d_in[7];
    float* out = (float*)d_out;

    const size_t gx_bytes = (size_t)B_ * S_ * G4 * sizeof(float);
    const size_t meta_bytes = 1 << 20;  // flags @0, hbuf @1024

    if (ws_size >= gx_bytes + meta_bytes) {
        int* flags = (int*)d_ws;
        unsigned short* hbuf = (unsigned short*)((char*)d_ws + 1024);
        float* Gx = (float*)((char*)d_ws + meta_bytes);
        hipMemsetAsync(d_ws, 0, 1024, stream);  // zero flags every launch
        gemm_xw<true><<<(B_ * S_) / 16, 256, 0, stream>>>(x, W, bias, Gx);
        plstm_mfma<<<64, 256, 0, stream>>>(ts, U, Periods, Shifts, OnEnd, Gx,
                                           out, hbuf, flags);
    } else if (ws_size >= gx_bytes) {
        float* Gx = (float*)d_ws;
        gemm_xw<false><<<(B_ * S_) / 16, 256, 0, stream>>>(x, W, bias, Gx);
        plstm_scan2<true><<<B_ / 2, 512, 0, stream>>>(x, ts, W, U, bias, Periods,
                                                      Shifts, OnEnd, Gx, out);
    } else {
        plstm_scan2<false><<<B_ / 2, 512, 0, stream>>>(x, ts, W, U, bias, Periods,
                                                       Shifts, OnEnd, nullptr, out);
    }
}

// Round 4
// 3811.387 us; speedup vs baseline: 4.2229x; 2.6084x over previous
//
#include <hip/hip_runtime.h>
#include <cstdint>
#include <cstddef>

#define B_ 128
#define S_ 1024
#define I_ 128
#define H_ 256
#define G4 1024  // 4*H
#define OFF_SLOPE 0.001f

typedef float f32x4 __attribute__((ext_vector_type(4)));
typedef short s16x8 __attribute__((ext_vector_type(8)));

__device__ __forceinline__ unsigned short f2bf_rne(float f) {
    unsigned int u = __builtin_bit_cast(unsigned int, f);
    u += 0x7FFFu + ((u >> 16) & 1u);
    return (unsigned short)(u >> 16);
}
__device__ __forceinline__ float bf2f(unsigned short h) {
    unsigned int u = ((unsigned int)h) << 16;
    return __builtin_bit_cast(float, u);
}
__device__ __forceinline__ float fsigmoid(float x) {
    return 1.0f / (1.0f + __expf(-x));
}
__device__ __forceinline__ float ftanh(float x) {
    return 2.0f / (1.0f + __expf(-2.0f * x)) - 1.0f;
}

// ---------------------------------------------------------------------------
// Kernel A: Gx = x @ W + bias.  SCANLAYOUT=true writes the MFMA-scan-friendly
// order [group*8+cb][t][16 b][128 lc]; false writes plain [b,t,1024].
// ---------------------------------------------------------------------------
template <bool SCANLAYOUT>
__global__ __launch_bounds__(256) void gemm_xw(const float* __restrict__ X,
                                               const float* __restrict__ W,
                                               const float* __restrict__ bias,
                                               float* __restrict__ Gx) {
    __shared__ float A_s[16 * 128];
    const int tid = threadIdx.x;
    const size_t row0 = (size_t)blockIdx.x * 16;

    for (int i = tid; i < 16 * 128; i += 256)
        A_s[i] = X[row0 * I_ + i];
    __syncthreads();

    const float4 bias4 = ((const float4*)bias)[tid];
    float4 acc[16];
#pragma unroll
    for (int r = 0; r < 16; ++r) acc[r] = bias4;

    const float4* W4 = (const float4*)W;
    for (int k = 0; k < I_; ++k) {
        float4 w = W4[k * 256 + tid];
#pragma unroll
        for (int r = 0; r < 16; ++r) {
            float a = A_s[r * 128 + k];
            acc[r].x = fmaf(a, w.x, acc[r].x);
            acc[r].y = fmaf(a, w.y, acc[r].y);
            acc[r].z = fmaf(a, w.z, acc[r].z);
            acc[r].w = fmaf(a, w.w, acc[r].w);
        }
    }
    if (SCANLAYOUT) {
        const int b = (int)(row0 >> 10);  // S_=1024
        const int t0 = (int)(row0 & 1023);
        const int g = b >> 4, bb = b & 15;
        const int n0 = 4 * tid;
        const int q = n0 >> 8, u = n0 & 255, cb = u >> 5, j = u & 31;
        const int lc = q * 32 + j;
#pragma unroll
        for (int r = 0; r < 16; ++r) {
            size_t idx = ((((size_t)(g * 8 + cb) * 1024 + (t0 + r)) * 16 + bb) * 128 + lc);
            *(float4*)&Gx[idx] = acc[r];
        }
    } else {
        float4* O4 = (float4*)Gx;
#pragma unroll
        for (int r = 0; r < 16; ++r)
            O4[(row0 + r) * 256 + tid] = acc[r];
    }
}

// ---------------------------------------------------------------------------
// Kernel B: MFMA phased-LSTM scan, relaxed-atomic (L2-bypass) sync protocol.
// Grid = 64 blocks x 256 threads. Block: g = blk&7 (batch group of 16 ->
// siblings share blk%8 -> same XCD under round-robin), cb = blk>>3 (owns
// hidden units [32*cb,32*cb+32)). U slice in registers as split-bf16 MFMA
// B-fragments. h exchanged per step via relaxed agent-scope (sc1, cache-
// bypassing) 8B atomics + a per-step arrival counter. NO acquire/release/
// threadfence -> no buffer_inv / buffer_wbl2 bulk cache ops.
// Ordering argument: sc1 stores are performed at the device coherence point
// when vmcnt retires; __syncthreads drains vmcnt before the barrier, so the
// tid0 fetch_add (issued after the barrier) is globally ordered after all of
// this block's h stores. A reader seeing ctr[t]==8 then issuing sc1 loads
// (pinned after the spin by a compiler memory barrier; waves issue in order)
// observes all 8 blocks' h.
// ---------------------------------------------------------------------------
__global__ __launch_bounds__(256, 1) void plstm_mfma(
    const float* __restrict__ ts, const float* __restrict__ U,
    const float* __restrict__ Periods, const float* __restrict__ Shifts,
    const float* __restrict__ OnEnd, const float* __restrict__ Gx,
    float* __restrict__ out, unsigned long long* __restrict__ hbuf,
    int* __restrict__ ctr) {
    const int blk = blockIdx.x;
    const int g = blk & 7;   // group -> all 8 siblings on same XCD
    const int cb = blk >> 3; // column block
    const int tid = threadIdx.x;
    const int w = tid >> 6;  // wave = gate index q
    const int l = tid & 63;
    const int lr = l & 15;   // tile row/col lane
    const int lg = l >> 4;   // k-group

    __shared__ unsigned short h_hi[16 * 264];
    __shared__ unsigned short h_lo[16 * 264];
    __shared__ float gates[4 * 16 * 33];

    // ---- stage U slice into registers as split-bf16 B-fragments ----
    // B-frag (16x16x32): lane l holds B[k=(l>>4)*8+i][col=l&15], i=0..7
    s16x8 Uhi[2][8], Ulo[2][8];
#pragma unroll
    for (int tt = 0; tt < 2; ++tt) {
        const int n = w * 256 + cb * 32 + tt * 16 + lr;  // global gate col
#pragma unroll
        for (int kk = 0; kk < 8; ++kk) {
            s16x8 hi8, lo8;
#pragma unroll
            for (int i = 0; i < 8; ++i) {
                int k = kk * 32 + lg * 8 + i;
                float uv = U[(size_t)k * G4 + n];
                unsigned short h = f2bf_rne(uv);
                float r = uv - bf2f(h);
                hi8[i] = (short)h;
                lo8[i] = (short)f2bf_rne(r);
            }
            Uhi[tt][kk] = hi8;
            Ulo[tt][kk] = lo8;
        }
    }

    // ---- elementwise identity: thread owns (batch eb, units u0, u0+1) ----
    const int eb = tid >> 4;
    const int ej = 2 * (tid & 15);
    const int u0 = cb * 32 + ej;  // global hidden unit
    const float per0 = fabsf(Periods[u0]), per1 = fabsf(Periods[u0 + 1]);
    const float sh0 = Shifts[u0], sh1 = Shifts[u0 + 1];
    const float oe0 = fabsf(OnEnd[u0]) * per0, oe1 = fabsf(OnEnd[u0 + 1]) * per1;
    const float om0 = 0.5f * oe0, om1 = 0.5f * oe1;
    const float iom0 = 1.0f / om0, iom1 = 1.0f / om1;
    const float ip0 = 1.0f / per0, ip1 = 1.0f / per1;

    float c0 = 0.f, c1 = 0.f, h0 = 0.f, h1 = 0.f;
    const float* tsrow = ts + (size_t)(g * 16 + eb) * S_;
    const float* gxbase = Gx + (size_t)(g * 8 + cb) * 1024 * 2048 + eb * 128;
    float* outrow = out + (size_t)(g * 16 + eb) * S_ * H_ + u0;

    unsigned long long* const hb0 = hbuf + (size_t)g * 2048;
    unsigned long long* const hb1 = hbuf + (size_t)(8 + g) * 2048;

    for (int i = tid; i < 16 * 264; i += 256) { h_hi[i] = 0; h_lo[i] = 0; }
    __syncthreads();

    const int abase = lr * 264 + lg * 8;
    const int pubidx = eb * 128 + cb * 16 + (tid & 15);
    const int b2 = tid >> 4, seg = tid & 15;  // refill mapping
    const int rbase = b2 * 128 + seg * 8;

    // prologue: Gx + ts for t=0
    float2 cq0 = *(const float2*)&gxbase[0 * 32 + ej];
    float2 cq1 = *(const float2*)&gxbase[1 * 32 + ej];
    float2 cq2 = *(const float2*)&gxbase[2 * 32 + ej];
    float2 cq3 = *(const float2*)&gxbase[3 * 32 + ej];
    float tsc = tsrow[0];

    for (int t = 0; t < S_; ++t) {
        // ---- MFMA: gates_partial = h @ Uslice (split-bf16, 3 products) ----
        f32x4 a0 = {0.f, 0.f, 0.f, 0.f}, a1 = {0.f, 0.f, 0.f, 0.f};
#pragma unroll
        for (int kk = 0; kk < 8; ++kk) {
            s16x8 ah = *(const s16x8*)&h_hi[abase + kk * 32];
            s16x8 al = *(const s16x8*)&h_lo[abase + kk * 32];
            a0 = __builtin_amdgcn_mfma_f32_16x16x32_bf16(ah, Uhi[0][kk], a0, 0, 0, 0);
            a0 = __builtin_amdgcn_mfma_f32_16x16x32_bf16(ah, Ulo[0][kk], a0, 0, 0, 0);
            a0 = __builtin_amdgcn_mfma_f32_16x16x32_bf16(al, Uhi[0][kk], a0, 0, 0, 0);
            a1 = __builtin_amdgcn_mfma_f32_16x16x32_bf16(ah, Uhi[1][kk], a1, 0, 0, 0);
            a1 = __builtin_amdgcn_mfma_f32_16x16x32_bf16(ah, Ulo[1][kk], a1, 0, 0, 0);
            a1 = __builtin_amdgcn_mfma_f32_16x16x32_bf16(al, Uhi[1][kk], a1, 0, 0, 0);
        }
        // C frag: row(batch) = lg*4+r, col = lr
#pragma unroll
        for (int r = 0; r < 4; ++r) {
            gates[(w * 16 + lg * 4 + r) * 33 + lr] = a0[r];
            gates[(w * 16 + lg * 4 + r) * 33 + 16 + lr] = a1[r];
        }
        __syncthreads();  // gates ready

        // ---- elementwise phased-LSTM update (2 units per thread) ----
        float i0 = gates[(0 * 16 + eb) * 33 + ej] + cq0.x;
        float f0 = gates[(1 * 16 + eb) * 33 + ej] + cq1.x;
        float g0 = gates[(2 * 16 + eb) * 33 + ej] + cq2.x;
        float o0 = gates[(3 * 16 + eb) * 33 + ej] + cq3.x;
        float i1 = gates[(0 * 16 + eb) * 33 + ej + 1] + cq0.y;
        float f1 = gates[(1 * 16 + eb) * 33 + ej + 1] + cq1.y;
        float g1 = gates[(2 * 16 + eb) * 33 + ej + 1] + cq2.y;
        float o1 = gates[(3 * 16 + eb) * 33 + ej + 1] + cq3.y;

        float it0 = fsigmoid(i0), ft0 = fsigmoid(f0);
        float gt0 = ftanh(g0), ot0 = fsigmoid(o0);
        float it1 = fsigmoid(i1), ft1 = fsigmoid(f1);
        float gt1 = ftanh(g1), ot1 = fsigmoid(o1);

        float cn0 = fmaf(ft0, c0, it0 * gt0);
        float hn0 = ot0 * ftanh(cn0);
        float cn1 = fmaf(ft1, c1, it1 * gt1);
        float hn1 = ot1 * ftanh(cn1);

        float ic0 = fmodf(tsc + sh0, per0);
        float m0 = (ic0 <= om0) ? ic0 * iom0
                 : (ic0 <= oe0) ? (oe0 - ic0) * iom0
                                : OFF_SLOPE * (ic0 * ip0);
        float ic1 = fmodf(tsc + sh1, per1);
        float m1 = (ic1 <= om1) ? ic1 * iom1
                 : (ic1 <= oe1) ? (oe1 - ic1) * iom1
                                : OFF_SLOPE * (ic1 * ip1);

        c0 = m0 * cn0 + (1.f - m0) * c0;
        c1 = m1 * cn1 + (1.f - m1) * c1;
        h0 = m0 * hn0 + (1.f - m0) * h0;
        h1 = m1 * hn1 + (1.f - m1) * h1;

        *(float2*)&outrow[(size_t)t * H_] = make_float2(h0, h1);

        // ---- publish split-bf16 h: one 8B relaxed agent store (sc1) ----
        unsigned int hiw = (unsigned int)f2bf_rne(h0) | ((unsigned int)f2bf_rne(h1) << 16);
        float r0 = h0 - bf2f(f2bf_rne(h0));
        float r1 = h1 - bf2f(f2bf_rne(h1));
        unsigned int low = (unsigned int)f2bf_rne(r0) | ((unsigned int)f2bf_rne(r1) << 16);
        unsigned long long pack = (unsigned long long)hiw |
                                  ((unsigned long long)low << 32);
        unsigned long long* hbp = (t & 1) ? hb1 : hb0;
        __hip_atomic_store(&hbp[pubidx], pack, __ATOMIC_RELAXED,
                           __HIP_MEMORY_SCOPE_AGENT);
        __syncthreads();  // vmcnt(0) drain: all h stores performed at L3

        // prefetch next step's Gx/ts here: next barrier is ~spin+refill away
        float2 nq0 = cq0, nq1 = cq1, nq2 = cq2, nq3 = cq3;
        float tsn = tsc;
        if (t + 1 < S_) {
            const float* gxn = gxbase + (size_t)(t + 1) * 2048;
            nq0 = *(const float2*)&gxn[0 * 32 + ej];
            nq1 = *(const float2*)&gxn[1 * 32 + ej];
            nq2 = *(const float2*)&gxn[2 * 32 + ej];
            nq3 = *(const float2*)&gxn[3 * 32 + ej];
            tsn = tsrow[t + 1];
        }

        if (tid == 0)
            __hip_atomic_fetch_add(&ctr[t], 1, __ATOMIC_RELAXED,
                                   __HIP_MEMORY_SCOPE_AGENT);
        {
            int guard = 0;
            while (__hip_atomic_load(&ctr[t], __ATOMIC_RELAXED,
                                     __HIP_MEMORY_SCOPE_AGENT) < 8) {
                if (++guard > (1 << 15)) break;  // bounded: never hang
            }
        }
        asm volatile("" ::: "memory");  // pin refill loads after the spin
        __builtin_amdgcn_sched_barrier(0);

        // ---- refill h LDS from group buffer via relaxed 8B loads ----
        {
            const unsigned long long* src = (t & 1) ? hb1 : hb0;
            unsigned long long v[8];
#pragma unroll
            for (int i = 0; i < 8; ++i)
                v[i] = __hip_atomic_load(&src[rbase + i], __ATOMIC_RELAXED,
                                         __HIP_MEMORY_SCOPE_AGENT);
            uint4 hA, hB, lA, lB;
            hA.x = (unsigned int)v[0]; hA.y = (unsigned int)v[1];
            hA.z = (unsigned int)v[2]; hA.w = (unsigned int)v[3];
            hB.x = (unsigned int)v[4]; hB.y = (unsigned int)v[5];
            hB.z = (unsigned int)v[6]; hB.w = (unsigned int)v[7];
            lA.x = (unsigned int)(v[0] >> 32); lA.y = (unsigned int)(v[1] >> 32);
            lA.z = (unsigned int)(v[2] >> 32); lA.w = (unsigned int)(v[3] >> 32);
            lB.x = (unsigned int)(v[4] >> 32); lB.y = (unsigned int)(v[5] >> 32);
            lB.z = (unsigned int)(v[6] >> 32); lB.w = (unsigned int)(v[7] >> 32);
            const int doff = b2 * 264 + seg * 16;  // shorts; 16B-aligned
            *(uint4*)&h_hi[doff] = hA;
            *(uint4*)&h_hi[doff + 8] = hB;
            *(uint4*)&h_lo[doff] = lA;
            *(uint4*)&h_lo[doff + 8] = lB;
        }
        __syncthreads();  // h LDS ready for next step's MFMA

        cq0 = nq0; cq1 = nq1; cq2 = nq2; cq3 = nq3; tsc = tsn;
    }

    const size_t fin = (size_t)B_ * S_ * H_;
    *(float2*)&out[fin + (size_t)(g * 16 + eb) * H_ + u0] = make_float2(h0, h1);
    *(float2*)&out[fin + (size_t)B_ * H_ + (size_t)(g * 16 + eb) * H_ + u0] =
        make_float2(c0, c1);
}

// ---------------------------------------------------------------------------
// Fallback (round-2 verified): VALU scan, NB=2 batches/block.
// ---------------------------------------------------------------------------
template <bool PRE>
__global__ __launch_bounds__(512) void plstm_scan2(
    const float* __restrict__ x, const float* __restrict__ ts,
    const float* __restrict__ W, const float* __restrict__ U,
    const float* __restrict__ bias, const float* __restrict__ Periods,
    const float* __restrict__ Shifts, const float* __restrict__ OnEnd,
    const float* __restrict__ Gx, float* __restrict__ out) {
    const int g = blockIdx.x;
    const int tid = threadIdx.x;
    const int lane = tid & 255;
    const int bb = tid >> 8;
    const int b0 = 2 * g, b1 = 2 * g + 1;
    const int bcur = b0 + bb;

    __shared__ float h_s[2][H_];
    __shared__ float gate_s[2][G4];
    __shared__ float x_s[2][I_];

    const float period = fabsf(Periods[lane]);
    const float shift = Shifts[lane];
    const float oe = fabsf(OnEnd[lane]);
    const float on_mid = oe * 0.5f * period;
    const float on_end = oe * period;
    const float inv_on_mid = 1.0f / on_mid;
    const float inv_period = 1.0f / period;

    ((float*)h_s)[tid] = 0.f;

    float c = 0.f, last_h = 0.f;
    float2 bias2 = make_float2(0.f, 0.f);
    if (!PRE) bias2 = ((const float2*)bias)[tid];

    const float2* W2 = (const float2*)W;
    const float2* U2 = (const float2*)U;
    const float2* Gx2 = (const float2*)Gx;
    const float* tsb = ts + (size_t)bcur * S_;
    const size_t obase = (size_t)bcur * S_ * H_;

    for (int t = 0; t < S_; ++t) {
        if (!PRE) {
            if (tid < 2 * I_)
                x_s[tid >> 7][tid & 127] =
                    x[((size_t)(b0 + (tid >> 7)) * S_ + t) * I_ + (tid & 127)];
        }
        __syncthreads();

        float2 a0, a1;
        if (PRE) {
            a0 = Gx2[((size_t)b0 * S_ + t) * (G4 / 2) + tid];
            a1 = Gx2[((size_t)b1 * S_ + t) * (G4 / 2) + tid];
        } else {
            a0 = bias2; a1 = bias2;
#pragma unroll 8
            for (int k = 0; k < I_; ++k) {
                float2 w = W2[k * (G4 / 2) + tid];
                float x0 = x_s[0][k], x1 = x_s[1][k];
                a0.x = fmaf(x0, w.x, a0.x);
                a0.y = fmaf(x0, w.y, a0.y);
                a1.x = fmaf(x1, w.x, a1.x);
                a1.y = fmaf(x1, w.y, a1.y);
            }
        }
#pragma unroll 8
        for (int k = 0; k < H_; ++k) {
            float2 u = U2[k * (G4 / 2) + tid];
            float hv0 = h_s[0][k], hv1 = h_s[1][k];
            a0.x = fmaf(hv0, u.x, a0.x);
            a0.y = fmaf(hv0, u.y, a0.y);
            a1.x = fmaf(hv1, u.x, a1.x);
            a1.y = fmaf(hv1, u.y, a1.y);
        }
        ((float2*)gate_s[0])[tid] = a0;
        ((float2*)gate_s[1])[tid] = a1;
        __syncthreads();

        {
            float ig = gate_s[bb][lane];
            float fg = gate_s[bb][H_ + lane];
            float gg = gate_s[bb][2 * H_ + lane];
            float og = gate_s[bb][3 * H_ + lane];
            float i_t = 1.f / (1.f + expf(-ig));
            float f_t = 1.f / (1.f + expf(-fg));
            float g_t = tanhf(gg);
            float o_t = 1.f / (1.f + expf(-og));
            float hp = h_s[bb][lane];
            float c_new = fmaf(f_t, c, i_t * g_t);
            float h_new = o_t * tanhf(c_new);

            float tv = tsb[t];
            float in_c = fmodf(tv + shift, period);
            float mask;
            if (in_c <= on_mid) mask = in_c * inv_on_mid;
            else if (in_c <= on_end) mask = (on_end - in_c) * inv_on_mid;
            else mask = OFF_SLOPE * (in_c * inv_period);

            c = mask * c_new + (1.f - mask) * c;
            float h2 = mask * h_new + (1.f - mask) * hp;
            h_s[bb][lane] = h2;
            out[obase + (size_t)t * H_ + lane] = h2;
            last_h = h2;
        }
    }

    out[(size_t)B_ * S_ * H_ + (size_t)bcur * H_ + lane] = last_h;
    out[(size_t)B_ * S_ * H_ + (size_t)B_ * H_ + (size_t)bcur * H_ + lane] = c;
}

// ---------------------------------------------------------------------------
extern "C" void kernel_launch(void* const* d_in, const int* in_sizes, int n_in,
                              void* d_out, int out_size, void* d_ws, size_t ws_size,
                              hipStream_t stream) {
    (void)in_sizes; (void)n_in; (void)out_size;
    const float* x = (const float*)d_in[0];
    const float* ts = (const float*)d_in[1];
    const float* W = (const float*)d_in[2];
    const float* U = (const float*)d_in[3];
    const float* bias = (const float*)d_in[4];
    const float* Periods = (const float*)d_in[5];
    const float* Shifts = (const float*)d_in[6];
    const float* OnEnd = (const float*)d_in[7];
    float* out = (float*)d_out;

    const size_t gx_bytes = (size_t)B_ * S_ * G4 * sizeof(float);
    const size_t meta_bytes = 1 << 20;  // ctr @0 (4KB), hbuf @4KB (256KB)

    if (ws_size >= gx_bytes + meta_bytes) {
        int* ctr = (int*)d_ws;
        unsigned long long* hbuf = (unsigned long long*)((char*)d_ws + 4096);
        float* Gx = (float*)((char*)d_ws + meta_bytes);
        hipMemsetAsync(d_ws, 0, 4096, stream);  // zero ctr every launch
        gemm_xw<true><<<(B_ * S_) / 16, 256, 0, stream>>>(x, W, bias, Gx);
        plstm_mfma<<<64, 256, 0, stream>>>(ts, U, Periods, Shifts, OnEnd, Gx,
                                           out, hbuf, ctr);
    } else if (ws_size >= gx_bytes) {
        float* Gx = (float*)d_ws;
        gemm_xw<false><<<(B_ * S_) / 16, 256, 0, stream>>>(x, W, bias, Gx);
        plstm_scan2<true><<<B_ / 2, 512, 0, stream>>>(x, ts, W, U, bias, Periods,
                                                      Shifts, OnEnd, Gx, out);
    } else {
        plstm_scan2<false><<<B_ / 2, 512, 0, stream>>>(x, ts, W, U, bias, Periods,
                                                       Shifts, OnEnd, nullptr, out);
    }
}

// Round 6
// 3599.974 us; speedup vs baseline: 4.4709x; 1.0587x over previous
//
#include <hip/hip_runtime.h>
#include <cstdint>
#include <cstddef>

#define B_ 128
#define S_ 1024
#define I_ 128
#define H_ 256
#define G4 1024  // 4*H
#define OFF_SLOPE 0.001f

typedef float f32x4 __attribute__((ext_vector_type(4)));
typedef short s16x8 __attribute__((ext_vector_type(8)));

__device__ __forceinline__ unsigned short f2bf_rne(float f) {
    unsigned int u = __builtin_bit_cast(unsigned int, f);
    u += 0x7FFFu + ((u >> 16) & 1u);
    return (unsigned short)(u >> 16);
}
__device__ __forceinline__ float bf2f(unsigned short h) {
    unsigned int u = ((unsigned int)h) << 16;
    return __builtin_bit_cast(float, u);
}
__device__ __forceinline__ float fsigmoid(float x) {
    return 1.0f / (1.0f + __expf(-x));
}
__device__ __forceinline__ float ftanh(float x) {
    return 2.0f / (1.0f + __expf(-2.0f * x)) - 1.0f;
}

// ---------------------------------------------------------------------------
// Kernel A: Gx = x @ W + bias.  SCANLAYOUT=true writes the MFMA-scan-friendly
// order [group*8+cb][t][16 b][128 lc]; false writes plain [b,t,1024].
// ---------------------------------------------------------------------------
template <bool SCANLAYOUT>
__global__ __launch_bounds__(256) void gemm_xw(const float* __restrict__ X,
                                               const float* __restrict__ W,
                                               const float* __restrict__ bias,
                                               float* __restrict__ Gx) {
    __shared__ float A_s[16 * 128];
    const int tid = threadIdx.x;
    const size_t row0 = (size_t)blockIdx.x * 16;

    for (int i = tid; i < 16 * 128; i += 256)
        A_s[i] = X[row0 * I_ + i];
    __syncthreads();

    const float4 bias4 = ((const float4*)bias)[tid];
    float4 acc[16];
#pragma unroll
    for (int r = 0; r < 16; ++r) acc[r] = bias4;

    const float4* W4 = (const float4*)W;
    for (int k = 0; k < I_; ++k) {
        float4 w = W4[k * 256 + tid];
#pragma unroll
        for (int r = 0; r < 16; ++r) {
            float a = A_s[r * 128 + k];
            acc[r].x = fmaf(a, w.x, acc[r].x);
            acc[r].y = fmaf(a, w.y, acc[r].y);
            acc[r].z = fmaf(a, w.z, acc[r].z);
            acc[r].w = fmaf(a, w.w, acc[r].w);
        }
    }
    if (SCANLAYOUT) {
        const int b = (int)(row0 >> 10);  // S_=1024
        const int t0 = (int)(row0 & 1023);
        const int g = b >> 4, bb = b & 15;
        const int n0 = 4 * tid;
        const int q = n0 >> 8, u = n0 & 255, cb = u >> 5, j = u & 31;
        const int lc = q * 32 + j;
#pragma unroll
        for (int r = 0; r < 16; ++r) {
            size_t idx = ((((size_t)(g * 8 + cb) * 1024 + (t0 + r)) * 16 + bb) * 128 + lc);
            *(float4*)&Gx[idx] = acc[r];
        }
    } else {
        float4* O4 = (float4*)Gx;
#pragma unroll
        for (int r = 0; r < 16; ++r)
            O4[(row0 + r) * 256 + tid] = acc[r];
    }
}

// ---------------------------------------------------------------------------
// Kernel B: MFMA phased-LSTM scan, TAG-IN-DATA sync.
// Grid = 64 blocks x 256 threads. g = blk&7 (batch group of 16; siblings on
// same XCD under round-robin), cb = blk>>3 (owns hidden units [32cb,32cb+32)).
// U slice in registers as split-bf16 MFMA B-fragments.
// Cross-block h exchange: each 8B word = {2 bf16 hi | 2 bf16 lo} with the
// LSB of BOTH lo shorts carrying the step-parity tag ((t>>1)&1). Words are
// written/read with single relaxed agent-scope (sc1, L2-bypass) 8B atomics,
// so tag+payload are atomic. Readers poll their own refill words until the
// tag matches -> poll IS the refill (one L3 round trip, no drain barrier,
// no counter, no cross-group coupling). hbuf is memset 0xFF per launch:
// poison tag = 1 blocks t=0/1 readers (expected tag 0) until real data.
// Writer may only reuse a buffer 2 steps later, and transitively depends on
// every reader's consumption through the h chain -> no overwrite hazard.
// ---------------------------------------------------------------------------
__global__ __launch_bounds__(256, 1) void plstm_mfma(
    const float* __restrict__ ts, const float* __restrict__ U,
    const float* __restrict__ Periods, const float* __restrict__ Shifts,
    const float* __restrict__ OnEnd, const float* __restrict__ Gx,
    float* __restrict__ out, unsigned long long* __restrict__ hbuf) {
    const int blk = blockIdx.x;
    const int g = blk & 7;   // group -> all 8 siblings on same XCD
    const int cb = blk >> 3; // column block
    const int tid = threadIdx.x;
    const int w = tid >> 6;  // wave = gate index q
    const int l = tid & 63;
    const int lr = l & 15;   // tile row/col lane
    const int lg = l >> 4;   // k-group

    __shared__ unsigned short h_hi[16 * 264];
    __shared__ unsigned short h_lo[16 * 264];
    __shared__ float gates[4 * 16 * 33];

    // ---- stage U slice into registers as split-bf16 B-fragments ----
    // B-frag (16x16x32): lane l holds B[k=(l>>4)*8+i][col=l&15], i=0..7
    s16x8 Uhi[2][8], Ulo[2][8];
#pragma unroll
    for (int tt = 0; tt < 2; ++tt) {
        const int n = w * 256 + cb * 32 + tt * 16 + lr;  // global gate col
#pragma unroll
        for (int kk = 0; kk < 8; ++kk) {
            s16x8 hi8, lo8;
#pragma unroll
            for (int i = 0; i < 8; ++i) {
                int k = kk * 32 + lg * 8 + i;
                float uv = U[(size_t)k * G4 + n];
                unsigned short h = f2bf_rne(uv);
                float r = uv - bf2f(h);
                hi8[i] = (short)h;
                lo8[i] = (short)f2bf_rne(r);
            }
            Uhi[tt][kk] = hi8;
            Ulo[tt][kk] = lo8;
        }
    }

    // ---- elementwise identity: thread owns (batch eb, units u0, u0+1) ----
    const int eb = tid >> 4;
    const int ej = 2 * (tid & 15);
    const int u0 = cb * 32 + ej;  // global hidden unit
    const float per0 = fabsf(Periods[u0]), per1 = fabsf(Periods[u0 + 1]);
    const float sh0 = Shifts[u0], sh1 = Shifts[u0 + 1];
    const float oe0 = fabsf(OnEnd[u0]) * per0, oe1 = fabsf(OnEnd[u0 + 1]) * per1;
    const float om0 = 0.5f * oe0, om1 = 0.5f * oe1;
    const float iom0 = 1.0f / om0, iom1 = 1.0f / om1;
    const float ip0 = 1.0f / per0, ip1 = 1.0f / per1;

    float c0 = 0.f, c1 = 0.f, h0 = 0.f, h1 = 0.f;
    const float* tsrow = ts + (size_t)(g * 16 + eb) * S_;
    const float* gxbase = Gx + (size_t)(g * 8 + cb) * 1024 * 2048 + eb * 128;
    float* outrow = out + (size_t)(g * 16 + eb) * S_ * H_ + u0;

    unsigned long long* const hb0 = hbuf + (size_t)g * 2048;
    unsigned long long* const hb1 = hbuf + (size_t)(8 + g) * 2048;

    for (int i = tid; i < 16 * 264; i += 256) { h_hi[i] = 0; h_lo[i] = 0; }
    __syncthreads();

    const int abase = lr * 264 + lg * 8;
    const int pubidx = eb * 128 + cb * 16 + (tid & 15);
    const int b2 = tid >> 4, seg = tid & 15;  // refill mapping
    const int rbase = b2 * 128 + seg * 8;

    // prologue: Gx + ts for t=0
    float2 cq0 = *(const float2*)&gxbase[0 * 32 + ej];
    float2 cq1 = *(const float2*)&gxbase[1 * 32 + ej];
    float2 cq2 = *(const float2*)&gxbase[2 * 32 + ej];
    float2 cq3 = *(const float2*)&gxbase[3 * 32 + ej];
    float tsc = tsrow[0];

    for (int t = 0; t < S_; ++t) {
        // ---- MFMA: gates_partial = h @ Uslice (split-bf16, 3 products) ----
        f32x4 a0 = {0.f, 0.f, 0.f, 0.f}, a1 = {0.f, 0.f, 0.f, 0.f};
#pragma unroll
        for (int kk = 0; kk < 8; ++kk) {
            s16x8 ah = *(const s16x8*)&h_hi[abase + kk * 32];
            s16x8 al = *(const s16x8*)&h_lo[abase + kk * 32];
            a0 = __builtin_amdgcn_mfma_f32_16x16x32_bf16(ah, Uhi[0][kk], a0, 0, 0, 0);
            a0 = __builtin_amdgcn_mfma_f32_16x16x32_bf16(ah, Ulo[0][kk], a0, 0, 0, 0);
            a0 = __builtin_amdgcn_mfma_f32_16x16x32_bf16(al, Uhi[0][kk], a0, 0, 0, 0);
            a1 = __builtin_amdgcn_mfma_f32_16x16x32_bf16(ah, Uhi[1][kk], a1, 0, 0, 0);
            a1 = __builtin_amdgcn_mfma_f32_16x16x32_bf16(ah, Ulo[1][kk], a1, 0, 0, 0);
            a1 = __builtin_amdgcn_mfma_f32_16x16x32_bf16(al, Uhi[1][kk], a1, 0, 0, 0);
        }
        // C frag: row(batch) = lg*4+r, col = lr
#pragma unroll
        for (int r = 0; r < 4; ++r) {
            gates[(w * 16 + lg * 4 + r) * 33 + lr] = a0[r];
            gates[(w * 16 + lg * 4 + r) * 33 + 16 + lr] = a1[r];
        }
        __syncthreads();  // gates ready; all h LDS reads of this step done

        // ---- elementwise phased-LSTM update (2 units per thread) ----
        float i0 = gates[(0 * 16 + eb) * 33 + ej] + cq0.x;
        float f0 = gates[(1 * 16 + eb) * 33 + ej] + cq1.x;
        float g0 = gates[(2 * 16 + eb) * 33 + ej] + cq2.x;
        float o0 = gates[(3 * 16 + eb) * 33 + ej] + cq3.x;
        float i1 = gates[(0 * 16 + eb) * 33 + ej + 1] + cq0.y;
        float f1 = gates[(1 * 16 + eb) * 33 + ej + 1] + cq1.y;
        float g1 = gates[(2 * 16 + eb) * 33 + ej + 1] + cq2.y;
        float o1 = gates[(3 * 16 + eb) * 33 + ej + 1] + cq3.y;

        float it0 = fsigmoid(i0), ft0 = fsigmoid(f0);
        float gt0 = ftanh(g0), ot0 = fsigmoid(o0);
        float it1 = fsigmoid(i1), ft1 = fsigmoid(f1);
        float gt1 = ftanh(g1), ot1 = fsigmoid(o1);

        float cn0 = fmaf(ft0, c0, it0 * gt0);
        float hn0 = ot0 * ftanh(cn0);
        float cn1 = fmaf(ft1, c1, it1 * gt1);
        float hn1 = ot1 * ftanh(cn1);

        float ic0 = fmodf(tsc + sh0, per0);
        float m0 = (ic0 <= om0) ? ic0 * iom0
                 : (ic0 <= oe0) ? (oe0 - ic0) * iom0
                                : OFF_SLOPE * (ic0 * ip0);
        float ic1 = fmodf(tsc + sh1, per1);
        float m1 = (ic1 <= om1) ? ic1 * iom1
                 : (ic1 <= oe1) ? (oe1 - ic1) * iom1
                                : OFF_SLOPE * (ic1 * ip1);

        c0 = m0 * cn0 + (1.f - m0) * c0;
        c1 = m1 * cn1 + (1.f - m1) * c1;
        h0 = m0 * hn0 + (1.f - m0) * h0;
        h1 = m1 * hn1 + (1.f - m1) * h1;

        *(float2*)&outrow[(size_t)t * H_] = make_float2(h0, h1);

        // ---- publish split-bf16 h with parity tag in lo LSBs (1 sc1 store) --
        const unsigned int want = ((t >> 1) & 1) ? 0x00010001u : 0u;
        unsigned int hiw = (unsigned int)f2bf_rne(h0) | ((unsigned int)f2bf_rne(h1) << 16);
        float r0 = h0 - bf2f(f2bf_rne(h0));
        float r1 = h1 - bf2f(f2bf_rne(h1));
        unsigned int low = (unsigned int)f2bf_rne(r0) | ((unsigned int)f2bf_rne(r1) << 16);
        low = (low & 0xFFFEFFFEu) | want;  // tag in both lo-short LSBs
        unsigned long long pack = (unsigned long long)hiw |
                                  ((unsigned long long)low << 32);
        unsigned long long* const hbp = (t & 1) ? hb1 : hb0;
        __hip_atomic_store(&hbp[pubidx], pack, __ATOMIC_RELAXED,
                           __HIP_MEMORY_SCOPE_AGENT);
        __builtin_amdgcn_sched_barrier(0);  // publish issued before anything below

        // prefetch next step's Gx/ts while the group's stores are in flight
        float2 nq0 = cq0, nq1 = cq1, nq2 = cq2, nq3 = cq3;
        float tsn = tsc;
        if (t + 1 < S_) {
            const float* gxn = gxbase + (size_t)(t + 1) * 2048;
            nq0 = *(const float2*)&gxn[0 * 32 + ej];
            nq1 = *(const float2*)&gxn[1 * 32 + ej];
            nq2 = *(const float2*)&gxn[2 * 32 + ej];
            nq3 = *(const float2*)&gxn[3 * 32 + ej];
            tsn = tsrow[t + 1];
        }

        // ---- poll own 8 refill words until tag matches: poll IS the refill --
        unsigned long long v[8];
        {
            const unsigned long long* src = (t & 1) ? hb1 : hb0;
            int guard = 0;
            bool all;
            do {
                all = true;
#pragma unroll
                for (int i = 0; i < 8; ++i)
                    v[i] = __hip_atomic_load(&src[rbase + i], __ATOMIC_RELAXED,
                                             __HIP_MEMORY_SCOPE_AGENT);
#pragma unroll
                for (int i = 0; i < 8; ++i)
                    all = all && (((unsigned int)(v[i] >> 32) & 0x00010001u) == want);
            } while (!all && ++guard < (1 << 14));  // bounded: never hang
        }

        // ---- write h LDS (hi/lo split) from polled words ----
        {
            uint4 hA, hB, lA, lB;
            hA.x = (unsigned int)v[0]; hA.y = (unsigned int)v[1];
            hA.z = (unsigned int)v[2]; hA.w = (unsigned int)v[3];
            hB.x = (unsigned int)v[4]; hB.y = (unsigned int)v[5];
            hB.z = (unsigned int)v[6]; hB.w = (unsigned int)v[7];
            lA.x = (unsigned int)(v[0] >> 32); lA.y = (unsigned int)(v[1] >> 32);
            lA.z = (unsigned int)(v[2] >> 32); lA.w = (unsigned int)(v[3] >> 32);
            lB.x = (unsigned int)(v[4] >> 32); lB.y = (unsigned int)(v[5] >> 32);
            lB.z = (unsigned int)(v[6] >> 32); lB.w = (unsigned int)(v[7] >> 32);
            const int doff = b2 * 264 + seg * 16;  // shorts; 16B-aligned
            *(uint4*)&h_hi[doff] = hA;
            *(uint4*)&h_hi[doff + 8] = hB;
            *(uint4*)&h_lo[doff] = lA;
            *(uint4*)&h_lo[doff + 8] = lB;
        }
        __syncthreads();  // h LDS ready for next step's MFMA

        cq0 = nq0; cq1 = nq1; cq2 = nq2; cq3 = nq3; tsc = tsn;
    }

    const size_t fin = (size_t)B_ * S_ * H_;
    *(float2*)&out[fin + (size_t)(g * 16 + eb) * H_ + u0] = make_float2(h0, h1);
    *(float2*)&out[fin + (size_t)B_ * H_ + (size_t)(g * 16 + eb) * H_ + u0] =
        make_float2(c0, c1);
}

// ---------------------------------------------------------------------------
// Fallback (round-2 verified): VALU scan, NB=2 batches/block.
// ---------------------------------------------------------------------------
template <bool PRE>
__global__ __launch_bounds__(512) void plstm_scan2(
    const float* __restrict__ x, const float* __restrict__ ts,
    const float* __restrict__ W, const float* __restrict__ U,
    const float* __restrict__ bias, const float* __restrict__ Periods,
    const float* __restrict__ Shifts, const float* __restrict__ OnEnd,
    const float* __restrict__ Gx, float* __restrict__ out) {
    const int g = blockIdx.x;
    const int tid = threadIdx.x;
    const int lane = tid & 255;
    const int bb = tid >> 8;
    const int b0 = 2 * g, b1 = 2 * g + 1;
    const int bcur = b0 + bb;

    __shared__ float h_s[2][H_];
    __shared__ float gate_s[2][G4];
    __shared__ float x_s[2][I_];

    const float period = fabsf(Periods[lane]);
    const float shift = Shifts[lane];
    const float oe = fabsf(OnEnd[lane]);
    const float on_mid = oe * 0.5f * period;
    const float on_end = oe * period;
    const float inv_on_mid = 1.0f / on_mid;
    const float inv_period = 1.0f / period;

    ((float*)h_s)[tid] = 0.f;

    float c = 0.f, last_h = 0.f;
    float2 bias2 = make_float2(0.f, 0.f);
    if (!PRE) bias2 = ((const float2*)bias)[tid];

    const float2* W2 = (const float2*)W;
    const float2* U2 = (const float2*)U;
    const float2* Gx2 = (const float2*)Gx;
    const float* tsb = ts + (size_t)bcur * S_;
    const size_t obase = (size_t)bcur * S_ * H_;

    for (int t = 0; t < S_; ++t) {
        if (!PRE) {
            if (tid < 2 * I_)
                x_s[tid >> 7][tid & 127] =
                    x[((size_t)(b0 + (tid >> 7)) * S_ + t) * I_ + (tid & 127)];
        }
        __syncthreads();

        float2 a0, a1;
        if (PRE) {
            a0 = Gx2[((size_t)b0 * S_ + t) * (G4 / 2) + tid];
            a1 = Gx2[((size_t)b1 * S_ + t) * (G4 / 2) + tid];
        } else {
            a0 = bias2; a1 = bias2;
#pragma unroll 8
            for (int k = 0; k < I_; ++k) {
                float2 w = W2[k * (G4 / 2) + tid];
                float x0 = x_s[0][k], x1 = x_s[1][k];
                a0.x = fmaf(x0, w.x, a0.x);
                a0.y = fmaf(x0, w.y, a0.y);
                a1.x = fmaf(x1, w.x, a1.x);
                a1.y = fmaf(x1, w.y, a1.y);
            }
        }
#pragma unroll 8
        for (int k = 0; k < H_; ++k) {
            float2 u = U2[k * (G4 / 2) + tid];
            float hv0 = h_s[0][k], hv1 = h_s[1][k];
            a0.x = fmaf(hv0, u.x, a0.x);
            a0.y = fmaf(hv0, u.y, a0.y);
            a1.x = fmaf(hv1, u.x, a1.x);
            a1.y = fmaf(hv1, u.y, a1.y);
        }
        ((float2*)gate_s[0])[tid] = a0;
        ((float2*)gate_s[1])[tid] = a1;
        __syncthreads();

        {
            float ig = gate_s[bb][lane];
            float fg = gate_s[bb][H_ + lane];
            float gg = gate_s[bb][2 * H_ + lane];
            float og = gate_s[bb][3 * H_ + lane];
            float i_t = 1.f / (1.f + expf(-ig));
            float f_t = 1.f / (1.f + expf(-fg));
            float g_t = tanhf(gg);
            float o_t = 1.f / (1.f + expf(-og));
            float hp = h_s[bb][lane];
            float c_new = fmaf(f_t, c, i_t * g_t);
            float h_new = o_t * tanhf(c_new);

            float tv = tsb[t];
            float in_c = fmodf(tv + shift, period);
            float mask;
            if (in_c <= on_mid) mask = in_c * inv_on_mid;
            else if (in_c <= on_end) mask = (on_end - in_c) * inv_on_mid;
            else mask = OFF_SLOPE * (in_c * inv_period);

            c = mask * c_new + (1.f - mask) * c;
            float h2 = mask * h_new + (1.f - mask) * hp;
            h_s[bb][lane] = h2;
            out[obase + (size_t)t * H_ + lane] = h2;
            last_h = h2;
        }
    }

    out[(size_t)B_ * S_ * H_ + (size_t)bcur * H_ + lane] = last_h;
    out[(size_t)B_ * S_ * H_ + (size_t)B_ * H_ + (size_t)bcur * H_ + lane] = c;
}

// ---------------------------------------------------------------------------
extern "C" void kernel_launch(void* const* d_in, const int* in_sizes, int n_in,
                              void* d_out, int out_size, void* d_ws, size_t ws_size,
                              hipStream_t stream) {
    (void)in_sizes; (void)n_in; (void)out_size;
    const float* x = (const float*)d_in[0];
    const float* ts = (const float*)d_in[1];
    const float* W = (const float*)d_in[2];
    const float* U = (const float*)d_in[3];
    const float* bias = (const float*)d_in[4];
    const float* Periods = (const float*)d_in[5];
    const float* Shifts = (const float*)d_in[6];
    const float* OnEnd = (const float*)d_in[7];
    float* out = (float*)d_out;

    const size_t gx_bytes = (size_t)B_ * S_ * G4 * sizeof(float);
    const size_t hbuf_bytes = 2 * 8 * 2048 * 8;  // 256 KB
    const size_t meta_bytes = 1 << 20;           // hbuf @0, Gx @1MB

    if (ws_size >= gx_bytes + meta_bytes) {
        unsigned long long* hbuf = (unsigned long long*)d_ws;
        float* Gx = (float*)((char*)d_ws + meta_bytes);
        // 0xFF poison => lo-short LSB tag = 1, blocks t=0/1 readers (want 0)
        hipMemsetAsync(d_ws, 0xFF, hbuf_bytes, stream);
        gemm_xw<true><<<(B_ * S_) / 16, 256, 0, stream>>>(x, W, bias, Gx);
        plstm_mfma<<<64, 256, 0, stream>>>(ts, U, Periods, Shifts, OnEnd, Gx,
                                           out, hbuf);
    } else if (ws_size >= gx_bytes) {
        float* Gx = (float*)d_ws;
        gemm_xw<false><<<(B_ * S_) / 16, 256, 0, stream>>>(x, W, bias, Gx);
        plstm_scan2<true><<<B_ / 2, 512, 0, stream>>>(x, ts, W, U, bias, Periods,
                                                      Shifts, OnEnd, Gx, out);
    } else {
        plstm_scan2<false><<<B_ / 2, 512, 0, stream>>>(x, ts, W, U, bias, Periods,
                                                       Shifts, OnEnd, nullptr, out);
    }
}